// Round 1
// baseline (378.780 us; speedup 1.0000x reference)
//
#include <hip/hip_runtime.h>

// PRCutBatchLoss: total = sum_{a,b,k} W[a,b]*(Pl[a,k]+Pr[b,k]-2*Pl[a,k]*Pr[b,k])/cp[k]
// Collapses to one streaming pass over W (256 MiB fp32) against rank-K side factors:
//   total = sum_{a,b} W[a,b] * ( L[a] + R[b] - 2*dot(Pl[a,:], Pr'[b,:]) )
// with Pr'[b,k] = Pr[b,k]/cp[k], R[b] = sum_k Pr'[b,k], L[a] = sum_k Pl[a,k]/cp[k].
// Memory-bound: floor = 268 MB / 6.3 TB/s ~= 43 us.

constexpr int K     = 10;   // clusters (fixed by problem)
constexpr int TM    = 32;   // rows per block
constexpr int BLOCK = 256;  // threads per block
constexpr int TN    = BLOCK * 4;  // 1024 columns per block (float4 per lane)

__global__ void prcut_zero_out(float* out) {
    if (threadIdx.x == 0) out[0] = 0.0f;
}

__global__ __launch_bounds__(BLOCK) void prcut_main(
    const float* __restrict__ W,
    const float* __restrict__ Pl,
    const float* __restrict__ Pr,
    const float* __restrict__ cp,
    float* __restrict__ out,
    int Bn)
{
    // inv[k] = 1/cp[k] -- once per thread, uniform broadcast loads
    float inv[K];
#pragma unroll
    for (int k = 0; k < K; ++k) inv[k] = 1.0f / cp[k];

    const int col4 = blockIdx.x * TN + threadIdx.x * 4;  // first of 4 columns
    const int a0   = blockIdx.y * TM;

    // Load + scale P_r for this thread's 4 columns; Pr rows are K=10 floats,
    // 4 consecutive b -> 160 contiguous bytes (L2-resident, one-time).
    float pr[4][K];
    float rs[4];
#pragma unroll
    for (int j = 0; j < 4; ++j) {
        const float* prp = Pr + (size_t)(col4 + j) * K;
        float s = 0.0f;
#pragma unroll
        for (int k = 0; k < K; ++k) {
            float v = prp[k] * inv[k];
            pr[j][k] = v;
            s += v;
        }
        rs[j] = s;
    }

    const float* wp = W + (size_t)a0 * Bn + col4;
    float acc = 0.0f;

#pragma unroll 4
    for (int r = 0; r < TM; ++r) {
        const float4 w = *reinterpret_cast<const float4*>(wp);
        wp += Bn;

        // wave-uniform P_l row (a0+r): broadcast loads, compute L[a] on the fly
        const float* plp = Pl + (size_t)(a0 + r) * K;
        float pl[K];
        float la = 0.0f;
#pragma unroll
        for (int k = 0; k < K; ++k) {
            pl[k] = plp[k];
            la = fmaf(pl[k], inv[k], la);
        }

        // 4 independent rank-K dots
        float d0 = 0.f, d1 = 0.f, d2 = 0.f, d3 = 0.f;
#pragma unroll
        for (int k = 0; k < K; ++k) {
            d0 = fmaf(pl[k], pr[0][k], d0);
            d1 = fmaf(pl[k], pr[1][k], d1);
            d2 = fmaf(pl[k], pr[2][k], d2);
            d3 = fmaf(pl[k], pr[3][k], d3);
        }

        const float c0 = fmaf(-2.0f, d0, la + rs[0]);
        const float c1 = fmaf(-2.0f, d1, la + rs[1]);
        const float c2 = fmaf(-2.0f, d2, la + rs[2]);
        const float c3 = fmaf(-2.0f, d3, la + rs[3]);

        acc = fmaf(w.x, c0, acc);
        acc = fmaf(w.y, c1, acc);
        acc = fmaf(w.z, c2, acc);
        acc = fmaf(w.w, c3, acc);
    }

    // wave(64) shuffle reduction
#pragma unroll
    for (int off = 32; off > 0; off >>= 1)
        acc += __shfl_down(acc, off, 64);

    __shared__ float wsum[BLOCK / 64];
    const int lane = threadIdx.x & 63;
    const int wid  = threadIdx.x >> 6;
    if (lane == 0) wsum[wid] = acc;
    __syncthreads();

    if (threadIdx.x == 0) {
        float s = 0.0f;
#pragma unroll
        for (int i = 0; i < BLOCK / 64; ++i) s += wsum[i];
        atomicAdd(out, s);  // device-scope by default: cross-XCD safe
    }
}

extern "C" void kernel_launch(void* const* d_in, const int* in_sizes, int n_in,
                              void* d_out, int out_size, void* d_ws, size_t ws_size,
                              hipStream_t stream) {
    const float* W  = (const float*)d_in[0];
    const float* Pl = (const float*)d_in[1];
    const float* Pr = (const float*)d_in[2];
    const float* cp = (const float*)d_in[3];
    float* out = (float*)d_out;

    const int Kn = in_sizes[3];          // 10
    const int A  = in_sizes[1] / Kn;     // 8192
    const int B  = in_sizes[2] / Kn;     // 8192

    // d_out is re-poisoned (0xAA) before every call; zero it in-stream so the
    // main kernel's atomics accumulate from 0. (Kernel launch = graph-safe.)
    prcut_zero_out<<<1, 64, 0, stream>>>(out);

    dim3 grid(B / TN, A / TM);           // 8 x 256 = 2048 blocks
    prcut_main<<<grid, BLOCK, 0, stream>>>(W, Pl, Pr, cp, out, B);
}

// Round 2
// 367.140 us; speedup vs baseline: 1.0317x; 1.0317x over previous
//
#include <hip/hip_runtime.h>

// PRCutBatchLoss: total = sum_{a,b,k} W[a,b]*(Pl[a,k]+Pr[b,k]-2*Pl[a,k]*Pr[b,k])/cp[k]
// One streaming pass over W (256 MiB fp32) against rank-K register-resident factors:
//   total = sum_{a,b} W[a,b] * ( L[a] + sum_k Pr'[b,k]*(1 - 2*Pl[a,k]) )
// with Pr'[b,k] = Pr[b,k]/cp[k], L[a] = sum_k Pl[a,k]/cp[k].
//
// R2 change vs R1: full-row blocks for perfectly CONTIGUOUS HBM streams.
// R1 read 4-KB chunks at 32-KB stride from 2048 concurrent blocks -> DRAM
// row-buffer thrash -> 0.71 TB/s. Now each block (1024 thr) covers one full
// 8192-col row (thread t owns cols 4t and 4096+4t; both loads are perfectly
// lane-contiguous 1-KB wave segments), TM=16 rows -> 512-KB contiguous slab
// per block, grid=512 (2 blocks/CU). Pr' stays register-stationary
// (pr[8][10]), so side traffic is one-time L2 reads only.

constexpr int K     = 10;    // clusters (fixed by problem)
constexpr int TM    = 16;    // rows per block
constexpr int BLOCK = 1024;  // threads per block (covers 4096 cols per stripe)

typedef float f4 __attribute__((ext_vector_type(4)));

__global__ void prcut_zero_out(float* out) {
    if (threadIdx.x == 0) out[0] = 0.0f;
}

__global__ __launch_bounds__(BLOCK) void prcut_main(
    const float* __restrict__ W,
    const float* __restrict__ Pl,
    const float* __restrict__ Pr,
    const float* __restrict__ cp,
    float* __restrict__ out,
    int Bn)
{
    // inv[k] = 1/cp[k] -- uniform, ~10 VGPR live for the whole kernel
    float inv[K];
#pragma unroll
    for (int k = 0; k < K; ++k) inv[k] = 1.0f / cp[k];

    const int t    = threadIdx.x;
    const int a0   = blockIdx.x * TM;
    const int c0   = 4 * t;        // stripe-0 columns c0..c0+3
    const int half = Bn >> 1;      // 4096: stripe-1 columns half+c0..half+c0+3

    // pr[j][k] = Pr[col_j][k] / cp[k]; cols j<4 -> c0+j, j>=4 -> half+c0+(j-4).
    // Per-thread 160 contiguous bytes, thread-stride 160 B -> fully coalesced,
    // one-time, L2/L3-resident (Pr is 320 KB).
    float pr[8][K];
#pragma unroll
    for (int g = 0; g < 2; ++g) {
#pragma unroll
        for (int j = 0; j < 4; ++j) {
            const float* p = Pr + (size_t)(g * half + c0 + j) * K;
#pragma unroll
            for (int k = 0; k < K; ++k) pr[g * 4 + j][k] = p[k] * inv[k];
        }
    }

    const float* wp = W + (size_t)a0 * Bn + c0;
    float acc = 0.0f;

#pragma unroll 2
    for (int r = 0; r < TM; ++r) {
        // Two perfectly-coalesced 16-B/lane loads: [row, c0) and [row, half+c0).
        const f4 w0 = __builtin_nontemporal_load(reinterpret_cast<const f4*>(wp));
        const f4 w1 = __builtin_nontemporal_load(reinterpret_cast<const f4*>(wp + half));
        wp += Bn;

        // wave-uniform P_l row: scalar broadcast loads
        const float* plp = Pl + (size_t)(a0 + r) * K;
        float la = 0.0f;
        float d[8];
#pragma unroll
        for (int j = 0; j < 8; ++j) d[j] = 0.0f;

#pragma unroll
        for (int k = 0; k < K; ++k) {
            const float plk = plp[k];
            la = fmaf(plk, inv[k], la);                 // L[a]
            const float qk = fmaf(-2.0f, plk, 1.0f);    // 1 - 2*Pl[a,k]
#pragma unroll
            for (int j = 0; j < 8; ++j) d[j] = fmaf(pr[j][k], qk, d[j]);
        }

        acc = fmaf(w0.x, la + d[0], acc);
        acc = fmaf(w0.y, la + d[1], acc);
        acc = fmaf(w0.z, la + d[2], acc);
        acc = fmaf(w0.w, la + d[3], acc);
        acc = fmaf(w1.x, la + d[4], acc);
        acc = fmaf(w1.y, la + d[5], acc);
        acc = fmaf(w1.z, la + d[6], acc);
        acc = fmaf(w1.w, la + d[7], acc);
    }

    // wave(64) shuffle reduction -> LDS -> one atomic per block
#pragma unroll
    for (int off = 32; off > 0; off >>= 1)
        acc += __shfl_down(acc, off, 64);

    __shared__ float wsum[BLOCK / 64];
    const int lane = threadIdx.x & 63;
    const int wid  = threadIdx.x >> 6;
    if (lane == 0) wsum[wid] = acc;
    __syncthreads();

    if (threadIdx.x == 0) {
        float s = 0.0f;
#pragma unroll
        for (int i = 0; i < BLOCK / 64; ++i) s += wsum[i];
        atomicAdd(out, s);  // device-scope: cross-XCD safe; 512 total
    }
}

extern "C" void kernel_launch(void* const* d_in, const int* in_sizes, int n_in,
                              void* d_out, int out_size, void* d_ws, size_t ws_size,
                              hipStream_t stream) {
    const float* W  = (const float*)d_in[0];
    const float* Pl = (const float*)d_in[1];
    const float* Pr = (const float*)d_in[2];
    const float* cp = (const float*)d_in[3];
    float* out = (float*)d_out;

    const int Kn = in_sizes[3];          // 10
    const int A  = in_sizes[1] / Kn;     // 8192
    const int B  = in_sizes[2] / Kn;     // 8192

    // d_out is re-poisoned (0xAA) before every call; zero it in-stream.
    prcut_zero_out<<<1, 64, 0, stream>>>(out);

    prcut_main<<<A / TM, BLOCK, 0, stream>>>(W, Pl, Pr, cp, out, B);
}

// Round 3
// 362.351 us; speedup vs baseline: 1.0453x; 1.0132x over previous
//
#include <hip/hip_runtime.h>

// PRCutBatchLoss: total = sum_{a,b,k} W[a,b]*(Pl[a,k]+Pr[b,k]-2*Pl[a,k]*Pr[b,k])/cp[k]
// One streaming pass over W (256 MiB fp32):
//   total = sum_{a,b} W[a,b] * ( L[a] + RS[b] - 2*dot(Pl[a,:], Pr'[b,:]) )
// with Pr'[b,k]=Pr[b,k]/cp[k], RS[b]=sum_k Pr'[b,k], L[a]=sum_k Pl[a,k]/cp[k].
//
// R3 vs R2: (1) 4 cols/thread (pr[4][10]=40 VGPR) -> ~95 VGPR live, fits the
// 128-VGPR cap of a 1024-thread block with NO scratch spills (R2's 8-col
// version needed ~140 -> spilled in the hot loop). (2) Each block streams a
// half-row slab: 16-KB contiguous per row, 512 blocks, 1/CU resident -> ~256
// wide DRAM streams (R1 had ~1536 narrow 4-KB streams -> row-buffer thrash).
// (3) Explicit depth-4 rolling prefetch (distinct wbuf regs, load issued every
// iter) -> sustained vmcnt(3)-style pipeline, ~64 KB in flight per CU.

constexpr int K     = 10;    // clusters (fixed by problem)
constexpr int TM    = 32;    // rows per block
constexpr int BLOCK = 1024;  // threads; covers a 4096-col half-row via float4
constexpr int P     = 4;     // prefetch depth (rows in flight per thread)

typedef float f4 __attribute__((ext_vector_type(4)));

__global__ void prcut_zero_out(float* out) {
    if (threadIdx.x == 0) out[0] = 0.0f;
}

__global__ __launch_bounds__(BLOCK) void prcut_main(
    const float* __restrict__ W,
    const float* __restrict__ Pl,
    const float* __restrict__ Pr,
    const float* __restrict__ cp,
    float* __restrict__ out,
    int Bn)
{
    float inv[K];
#pragma unroll
    for (int k = 0; k < K; ++k) inv[k] = 1.0f / cp[k];

    // grid = (2 column halves, A/TM row bands)
    const int half = Bn >> 1;                            // 4096
    const int c0   = blockIdx.x * half + threadIdx.x * 4;
    const int a0   = blockIdx.y * TM;

    // Register-stationary scaled Pr' for this thread's 4 columns + row-sums.
    float pr[4][K];
    float rs[4];
#pragma unroll
    for (int j = 0; j < 4; ++j) {
        const float* p = Pr + (size_t)(c0 + j) * K;
        float s = 0.0f;
#pragma unroll
        for (int k = 0; k < K; ++k) {
            float v = p[k] * inv[k];
            pr[j][k] = v;
            s += v;
        }
        rs[j] = s;
    }

    const float* wp  = W + (size_t)a0 * Bn + c0;   // consume pointer (row 0)
    const float* wld = wp + (size_t)P * Bn;        // prefetch pointer (row P)

    // Prime the pipeline: P rows in flight, distinct registers.
    f4 wbuf[P];
#pragma unroll
    for (int i = 0; i < P; ++i)
        wbuf[i] = *reinterpret_cast<const f4*>(wp + (size_t)i * Bn);

    float acc = 0.0f;

#pragma unroll 4
    for (int r = 0; r < TM - P; ++r) {
        // Wave-uniform row coefficients (scalar loads; hidden by other waves).
        const float* plp = Pl + (size_t)(a0 + r) * K;
        float la = 0.0f;
#pragma unroll
        for (int k = 0; k < K; ++k) la = fmaf(plp[k], inv[k], la);

        float d0 = 0.f, d1 = 0.f, d2 = 0.f, d3 = 0.f;
#pragma unroll
        for (int k = 0; k < K; ++k) {
            const float plk = plp[k];
            d0 = fmaf(plk, pr[0][k], d0);
            d1 = fmaf(plk, pr[1][k], d1);
            d2 = fmaf(plk, pr[2][k], d2);
            d3 = fmaf(plk, pr[3][k], d3);
        }

        const int slot = r & (P - 1);
        const f4 w = wbuf[slot];                   // waits vmcnt(P-1) only
        wbuf[slot] = *reinterpret_cast<const f4*>(wld);  // keep P in flight
        wld += Bn;

        acc = fmaf(w.x, fmaf(-2.0f, d0, la + rs[0]), acc);
        acc = fmaf(w.y, fmaf(-2.0f, d1, la + rs[1]), acc);
        acc = fmaf(w.z, fmaf(-2.0f, d2, la + rs[2]), acc);
        acc = fmaf(w.w, fmaf(-2.0f, d3, la + rs[3]), acc);
    }

    // Drain the last P rows (no more prefetch).
#pragma unroll
    for (int r = TM - P; r < TM; ++r) {
        const float* plp = Pl + (size_t)(a0 + r) * K;
        float la = 0.0f;
#pragma unroll
        for (int k = 0; k < K; ++k) la = fmaf(plp[k], inv[k], la);

        float d0 = 0.f, d1 = 0.f, d2 = 0.f, d3 = 0.f;
#pragma unroll
        for (int k = 0; k < K; ++k) {
            const float plk = plp[k];
            d0 = fmaf(plk, pr[0][k], d0);
            d1 = fmaf(plk, pr[1][k], d1);
            d2 = fmaf(plk, pr[2][k], d2);
            d3 = fmaf(plk, pr[3][k], d3);
        }

        const f4 w = wbuf[r & (P - 1)];
        acc = fmaf(w.x, fmaf(-2.0f, d0, la + rs[0]), acc);
        acc = fmaf(w.y, fmaf(-2.0f, d1, la + rs[1]), acc);
        acc = fmaf(w.z, fmaf(-2.0f, d2, la + rs[2]), acc);
        acc = fmaf(w.w, fmaf(-2.0f, d3, la + rs[3]), acc);
    }

    // wave(64) shuffle reduction -> LDS -> one atomic per block
#pragma unroll
    for (int off = 32; off > 0; off >>= 1)
        acc += __shfl_down(acc, off, 64);

    __shared__ float wsum[BLOCK / 64];
    const int lane = threadIdx.x & 63;
    const int wid  = threadIdx.x >> 6;
    if (lane == 0) wsum[wid] = acc;
    __syncthreads();

    if (threadIdx.x == 0) {
        float s = 0.0f;
#pragma unroll
        for (int i = 0; i < BLOCK / 64; ++i) s += wsum[i];
        atomicAdd(out, s);  // device-scope: cross-XCD safe; 512 total
    }
}

extern "C" void kernel_launch(void* const* d_in, const int* in_sizes, int n_in,
                              void* d_out, int out_size, void* d_ws, size_t ws_size,
                              hipStream_t stream) {
    const float* W  = (const float*)d_in[0];
    const float* Pl = (const float*)d_in[1];
    const float* Pr = (const float*)d_in[2];
    const float* cp = (const float*)d_in[3];
    float* out = (float*)d_out;

    const int Kn = in_sizes[3];          // 10
    const int A  = in_sizes[1] / Kn;     // 8192
    const int B  = in_sizes[2] / Kn;     // 8192

    // d_out is re-poisoned (0xAA) before every call; zero it in-stream.
    prcut_zero_out<<<1, 64, 0, stream>>>(out);

    dim3 grid(2, A / TM);                // 512 blocks, 1 resident per CU
    prcut_main<<<grid, BLOCK, 0, stream>>>(W, Pl, Pr, cp, out, B);
}

// Round 4
// 349.852 us; speedup vs baseline: 1.0827x; 1.0357x over previous
//
#include <hip/hip_runtime.h>

// PRCutBatchLoss: total = sum_{a,b,k} W[a,b]*(Pl[a,k]+Pr[b,k]-2*Pl[a,k]*Pr[b,k])/cp[k]
// One streaming pass over W (256 MiB fp32):
//   total = sum_{a,b} W[a,b] * ( la[a] + rs[b] + sum_k q[a,k]*pr'[b,k] )
// with pr'[b,k]=Pr[b,k]/cp[k], rs[b]=sum_k pr'[b,k],
//      la[a]=sum_k Pl[a,k]/cp[k], q[a,k] = -2*Pl[a,k].
//
// R4 vs R3: occupancy attack. R3's 1024-thr block needed ~95 VGPR -> 1
// block/CU = 4 waves/SIMD -> half the memory-level parallelism. Now:
//  - 2 cols/thread (pr[2][10]=20 VGPR) and Pl folded OFF the hot path by a
//    pre-kernel into per-row records [la, q0..q9] in d_ws; row coeffs load
//    via uniform-address s_loads (SGPRs, not VGPRs).
//  - __launch_bounds__(1024, 8) caps VGPR at 64 -> 2 blocks/CU = 8 waves/SIMD.
//  - Block streams 2048 contiguous cols (8-KB chunk/row), TM=32, grid 1024.
//  - Depth-4 rolling float2 prefetch: 32 waves/CU x 1 KB = 32 KB in flight.

constexpr int K     = 10;    // clusters (fixed by problem)
constexpr int REC   = 12;    // per-row record: [la, q0..q9, pad] (48 B)
constexpr int TM    = 32;    // rows per block
constexpr int BLOCK = 1024;  // threads per block
constexpr int COLS  = BLOCK * 2;  // 2048 contiguous columns per block
constexpr int P     = 4;     // prefetch depth (rows in flight per thread)

typedef float f2 __attribute__((ext_vector_type(2)));

// Fold Pl/cp into per-row records; also zero the output accumulator.
__global__ void prcut_prep(const float* __restrict__ Pl,
                           const float* __restrict__ cp,
                           float* __restrict__ rec,
                           float* __restrict__ out, int A)
{
    const int a = blockIdx.x * blockDim.x + threadIdx.x;
    if (a == 0) out[0] = 0.0f;
    if (a >= A) return;
    float la = 0.0f;
    float r[REC];
#pragma unroll
    for (int k = 0; k < K; ++k) {
        const float p = Pl[(size_t)a * K + k];
        la = fmaf(p, 1.0f / cp[k], la);
        r[1 + k] = -2.0f * p;
    }
    r[0] = la;
    r[11] = 0.0f;
#pragma unroll
    for (int k = 0; k < REC; ++k) rec[(size_t)a * REC + k] = r[k];
}

__global__ __launch_bounds__(BLOCK, 8) void prcut_main(
    const float* __restrict__ W,
    const float* __restrict__ Pr,
    const float* __restrict__ cp,
    const float* __restrict__ rec,
    float* __restrict__ out,
    int Bn)
{
    const int c0 = blockIdx.x * COLS + threadIdx.x * 2;
    const int a0 = blockIdx.y * TM;

    // Register-stationary scaled pr' for this thread's 2 columns (+ rowsums).
    // inv[] lives only during init, then dies.
    float pr[2][K];
    float rs[2];
#pragma unroll
    for (int j = 0; j < 2; ++j) {
        const float* p = Pr + (size_t)(c0 + j) * K;
        float s = 0.0f;
#pragma unroll
        for (int k = 0; k < K; ++k) {
            const float v = p[k] * (1.0f / cp[k]);
            pr[j][k] = v;
            s += v;
        }
        rs[j] = s;
    }

    const float* wp  = W + (size_t)a0 * Bn + c0;   // consume pointer
    const float* wld = wp + (size_t)P * Bn;        // prefetch pointer

    f2 wbuf[P];
#pragma unroll
    for (int i = 0; i < P; ++i)
        wbuf[i] = __builtin_nontemporal_load(
            reinterpret_cast<const f2*>(wp + (size_t)i * Bn));

    float acc = 0.0f;
    const float* rp = rec + (size_t)a0 * REC;      // uniform -> s_loads

#pragma unroll 4
    for (int r = 0; r < TM - P; ++r) {
        const float la = rp[0];
        float d0 = la + rs[0];
        float d1 = la + rs[1];
#pragma unroll
        for (int k = 0; k < K; ++k) {
            const float q = rp[1 + k];             // SGPR operand
            d0 = fmaf(q, pr[0][k], d0);
            d1 = fmaf(q, pr[1][k], d1);
        }
        rp += REC;

        const int slot = r & (P - 1);
        const f2 w = wbuf[slot];                   // waits vmcnt(P-1) only
        wbuf[slot] = __builtin_nontemporal_load(
            reinterpret_cast<const f2*>(wld));
        wld += Bn;

        acc = fmaf(w.x, d0, fmaf(w.y, d1, acc));
    }

    // Drain the last P rows (no further prefetch).
#pragma unroll
    for (int r = TM - P; r < TM; ++r) {
        const float la = rp[0];
        float d0 = la + rs[0];
        float d1 = la + rs[1];
#pragma unroll
        for (int k = 0; k < K; ++k) {
            const float q = rp[1 + k];
            d0 = fmaf(q, pr[0][k], d0);
            d1 = fmaf(q, pr[1][k], d1);
        }
        rp += REC;

        const f2 w = wbuf[r & (P - 1)];
        acc = fmaf(w.x, d0, fmaf(w.y, d1, acc));
    }

    // wave(64) shuffle reduction -> LDS -> one atomic per block
#pragma unroll
    for (int off = 32; off > 0; off >>= 1)
        acc += __shfl_down(acc, off, 64);

    __shared__ float wsum[BLOCK / 64];
    const int lane = threadIdx.x & 63;
    const int wid  = threadIdx.x >> 6;
    if (lane == 0) wsum[wid] = acc;
    __syncthreads();

    if (threadIdx.x == 0) {
        float s = 0.0f;
#pragma unroll
        for (int i = 0; i < BLOCK / 64; ++i) s += wsum[i];
        atomicAdd(out, s);  // device-scope: cross-XCD safe; 1024 total
    }
}

extern "C" void kernel_launch(void* const* d_in, const int* in_sizes, int n_in,
                              void* d_out, int out_size, void* d_ws, size_t ws_size,
                              hipStream_t stream) {
    const float* W  = (const float*)d_in[0];
    const float* Pl = (const float*)d_in[1];
    const float* Pr = (const float*)d_in[2];
    const float* cp = (const float*)d_in[3];
    float* out = (float*)d_out;
    float* rec = (float*)d_ws;           // 8192*12*4 B = 384 KB of scratch

    const int Kn = in_sizes[3];          // 10
    const int A  = in_sizes[1] / Kn;     // 8192
    const int B  = in_sizes[2] / Kn;     // 8192

    // Fold Pl -> [la, q0..q9] records; zero d_out (it's poisoned every call).
    prcut_prep<<<(A + 255) / 256, 256, 0, stream>>>(Pl, cp, rec, out, A);

    dim3 grid(B / COLS, A / TM);         // 4 x 256 = 1024 blocks, 2/CU
    prcut_main<<<grid, BLOCK, 0, stream>>>(W, Pr, cp, rec, out, B);
}

// Round 5
// 349.712 us; speedup vs baseline: 1.0831x; 1.0004x over previous
//
#include <hip/hip_runtime.h>

// PRCutBatchLoss: total = sum_{a,b,k} W[a,b]*(Pl[a,k]+Pr[b,k]-2*Pl[a,k]*Pr[b,k])/cp[k]
// One streaming pass over W (256 MiB fp32):
//   total = sum_{a,b} W[a,b] * ( la[a] + rs[b] + sum_k q[a,k]*pr'[b,k] )
// with pr'[b,k]=Pr[b,k]/cp[k], rs[b]=sum_k pr'[b,k],
//      la[a]=sum_k Pl[a,k]/cp[k], q[a,k] = -2*Pl[a,k].
//
// R5 vs R4: pipeline hygiene.
//  (1) Row records (la,q0..q9) staged into LDS once per block (384 floats, one
//      barrier); in-loop they arrive via 3 broadcast ds_read_b128 -> lgkmcnt.
//      R4 loaded them from global INSIDE the loop -> ~11 vector loads/iter
//      interleaved into the same vmcnt FIFO as the W prefetch, forcing the
//      W-consume waitcnt to cover them. Now vmcnt carries ONLY W loads.
//  (2) float4 (16 B/lane) nontemporal W loads: 1 KB/wave-inst, half the VMEM
//      instruction count of R4's float2.
//  (3) __launch_bounds__(512, 6): 85-VGPR cap fits pr[4][10]+wbuf[2] (~66
//      live) with no spills; 24 waves/CU, P=2 -> 48 KB in flight per CU.

constexpr int K     = 10;    // clusters (fixed by problem)
constexpr int REC   = 12;    // per-row record: [la, q0..q9, pad] (48 B)
constexpr int TM    = 32;    // rows per block
constexpr int BLOCK = 512;   // threads per block
constexpr int COLS  = BLOCK * 4;  // 2048 contiguous columns per block
constexpr int P     = 2;     // prefetch depth (rows in flight per thread)

typedef float f4 __attribute__((ext_vector_type(4)));

// Fold Pl/cp into per-row records; also zero the output accumulator.
__global__ void prcut_prep(const float* __restrict__ Pl,
                           const float* __restrict__ cp,
                           float* __restrict__ rec,
                           float* __restrict__ out, int A)
{
    const int a = blockIdx.x * blockDim.x + threadIdx.x;
    if (a == 0) out[0] = 0.0f;
    if (a >= A) return;
    float la = 0.0f;
    float r[REC];
#pragma unroll
    for (int k = 0; k < K; ++k) {
        const float p = Pl[(size_t)a * K + k];
        la = fmaf(p, 1.0f / cp[k], la);
        r[1 + k] = -2.0f * p;
    }
    r[0]  = la;
    r[11] = 0.0f;
#pragma unroll
    for (int k = 0; k < REC; ++k) rec[(size_t)a * REC + k] = r[k];
}

__global__ __launch_bounds__(BLOCK, 6) void prcut_main(
    const float* __restrict__ W,
    const float* __restrict__ Pr,
    const float* __restrict__ cp,
    const float* __restrict__ rec,
    float* __restrict__ out,
    int Bn)
{
    // --- Stage this row-band's records into LDS (one-time, pre-barrier) ---
    __shared__ f4 lrec[TM * REC / 4];          // 96 x f4 = 384 floats = 1.5 KB
    const int t  = threadIdx.x;
    const int a0 = blockIdx.y * TM;
    if (t < TM * REC) ((float*)lrec)[t] = rec[(size_t)a0 * REC + t];

    // --- Register-stationary scaled pr' for this thread's 4 columns ---
    const int c0 = blockIdx.x * COLS + t * 4;
    float pr[4][K];
    float rs[4];
#pragma unroll
    for (int j = 0; j < 4; ++j) {
        const float* p = Pr + (size_t)(c0 + j) * K;
        float s = 0.0f;
#pragma unroll
        for (int k = 0; k < K; ++k) {
            const float v = p[k] * (1.0f / cp[k]);
            pr[j][k] = v;
            s += v;
        }
        rs[j] = s;
    }
    __syncthreads();

    // --- W pipeline: vmcnt carries ONLY these loads ---
    const float* wp  = W + (size_t)a0 * Bn + c0;
    const float* wld = wp + (size_t)P * Bn;

    f4 wbuf[P];
#pragma unroll
    for (int i = 0; i < P; ++i)
        wbuf[i] = __builtin_nontemporal_load(
            reinterpret_cast<const f4*>(wp + (size_t)i * Bn));

    float acc = 0.0f;

#pragma unroll 4
    for (int r = 0; r < TM - P; ++r) {
        // Broadcast row coefficients from LDS (lgkmcnt, conflict-free).
        const f4 qa = lrec[r * 3 + 0];   // {la, q0, q1, q2}
        const f4 qb = lrec[r * 3 + 1];   // {q3, q4, q5, q6}
        const f4 qc = lrec[r * 3 + 2];   // {q7, q8, q9, 0}
        const float la = qa.x;
        const float qv[K] = {qa.y, qa.z, qa.w, qb.x, qb.y,
                             qb.z, qb.w, qc.x, qc.y, qc.z};

        float d[4];
#pragma unroll
        for (int j = 0; j < 4; ++j) d[j] = la + rs[j];
#pragma unroll
        for (int k = 0; k < K; ++k) {
#pragma unroll
            for (int j = 0; j < 4; ++j) d[j] = fmaf(qv[k], pr[j][k], d[j]);
        }

        const int slot = r & (P - 1);
        const f4 w = wbuf[slot];                    // waits vmcnt(P-1) only
        wbuf[slot] = __builtin_nontemporal_load(
            reinterpret_cast<const f4*>(wld));
        wld += Bn;

        acc = fmaf(w.x, d[0], acc);
        acc = fmaf(w.y, d[1], acc);
        acc = fmaf(w.z, d[2], acc);
        acc = fmaf(w.w, d[3], acc);
    }

    // Drain the last P rows (no further prefetch).
#pragma unroll
    for (int r = TM - P; r < TM; ++r) {
        const f4 qa = lrec[r * 3 + 0];
        const f4 qb = lrec[r * 3 + 1];
        const f4 qc = lrec[r * 3 + 2];
        const float la = qa.x;
        const float qv[K] = {qa.y, qa.z, qa.w, qb.x, qb.y,
                             qb.z, qb.w, qc.x, qc.y, qc.z};

        float d[4];
#pragma unroll
        for (int j = 0; j < 4; ++j) d[j] = la + rs[j];
#pragma unroll
        for (int k = 0; k < K; ++k) {
#pragma unroll
            for (int j = 0; j < 4; ++j) d[j] = fmaf(qv[k], pr[j][k], d[j]);
        }

        const f4 w = wbuf[r & (P - 1)];
        acc = fmaf(w.x, d[0], acc);
        acc = fmaf(w.y, d[1], acc);
        acc = fmaf(w.z, d[2], acc);
        acc = fmaf(w.w, d[3], acc);
    }

    // wave(64) shuffle reduction -> LDS -> one atomic per block
#pragma unroll
    for (int off = 32; off > 0; off >>= 1)
        acc += __shfl_down(acc, off, 64);

    __shared__ float wsum[BLOCK / 64];
    const int lane = t & 63;
    const int wid  = t >> 6;
    if (lane == 0) wsum[wid] = acc;
    __syncthreads();

    if (t == 0) {
        float s = 0.0f;
#pragma unroll
        for (int i = 0; i < BLOCK / 64; ++i) s += wsum[i];
        atomicAdd(out, s);  // device-scope: cross-XCD safe; 1024 total
    }
}

extern "C" void kernel_launch(void* const* d_in, const int* in_sizes, int n_in,
                              void* d_out, int out_size, void* d_ws, size_t ws_size,
                              hipStream_t stream) {
    const float* W  = (const float*)d_in[0];
    const float* Pl = (const float*)d_in[1];
    const float* Pr = (const float*)d_in[2];
    const float* cp = (const float*)d_in[3];
    float* out = (float*)d_out;
    float* rec = (float*)d_ws;           // 8192*12*4 B = 384 KB of scratch

    const int Kn = in_sizes[3];          // 10
    const int A  = in_sizes[1] / Kn;     // 8192
    const int B  = in_sizes[2] / Kn;     // 8192

    // Fold Pl -> [la, q0..q9] records; zero d_out (poisoned every call).
    prcut_prep<<<(A + 255) / 256, 256, 0, stream>>>(Pl, cp, rec, out, A);

    dim3 grid(B / COLS, A / TM);         // 4 x 256 = 1024 blocks, 3/CU
    prcut_main<<<grid, BLOCK, 0, stream>>>(W, Pr, cp, rec, out, B);
}